// Round 20
// baseline (906.859 us; speedup 1.0000x reference)
//
#include <hip/hip_runtime.h>
#include <cstdint>
#include <cstddef>

#define NN 100000      // nodes
#define NE 1600000     // edges
#define FD 128         // feature dim
#define HD2 256        // hidden*2
#define NLAYERS 4
#define NGR 512        // graphs
#define NCLS 10
#define BNEPS 1e-5f
#define G1TILES 1563   // ceil(NN/64)
#define GEMM_GRID 512  // zstat grid: 2 blocks/CU co-resident exactly
#define MLP_GRID 256   // k_mlp grid (1 block/CU)
#define EB 6250        // edge blocks (NE/256)
#define NB 391         // node blocks ceil(NN/256)
#define NSLICE 8       // XCD slices for scatter/deg
#define SLICEW 12500   // node range per slice (NN/8)

typedef unsigned short ushort_t;
typedef short bf16x8 __attribute__((ext_vector_type(8)));
typedef float f32x4 __attribute__((ext_vector_type(4)));

__device__ __forceinline__ float bfl(unsigned short u) {
  unsigned v = ((unsigned)u) << 16;
  return __builtin_bit_cast(float, v);
}
__device__ __forceinline__ unsigned short fbf(float f) {
  unsigned u = __builtin_bit_cast(unsigned, f);
  unsigned r = (u + 0x7FFFu + ((u >> 16) & 1u)) >> 16;
  return (unsigned short)r;
}

// ---------------- fused init (degi=0) + int64 detect ----------------
__global__ void k_init_detect(const int* ei, int* flag, int* degi) {
  int i = blockIdx.x * 256 + threadIdx.x;
  if (i < NN) degi[i] = 0;
  if (blockIdx.x == 0) {
    __shared__ int nz;
    if (threadIdx.x == 0) nz = 0;
    __syncthreads();
    if (ei[2 * threadIdx.x + 1] != 0) atomicAdd(&nz, 1);
    __syncthreads();
    if (threadIdx.x == 0) flag[0] = (nz == 0) ? 1 : 0;  // 1 => int64
  }
}

// ---------------- pure repack ----------------
__global__ void k_repack(const int* ei, const int* batch, const int* flag,
                         int* src32, int* dst32, int* batch32) {
  int i = blockIdx.x * 256 + threadIdx.x;
  const bool wide = (flag[0] != 0);
  if (i < NE) {
    src32[i] = wide ? ei[2 * i] : ei[i];
    dst32[i] = wide ? ei[2 * (NE + i)] : ei[NE + i];
  }
  if (i < NN) batch32[i] = wide ? batch[2 * i] : batch[i];
}

// ---------------- XCD-sliced degree histogram ----------------
__global__ void k_deg8(const int* __restrict__ dst, int* degi) {
  int slice = blockIdx.x & (NSLICE - 1);
  int e = (blockIdx.x >> 3) * 256 + threadIdx.x;
  if (e >= NE) return;
  int d = dst[e];
  int lo = slice * SLICEW;
  if (d >= lo && d < lo + SLICEW) atomicAdd(&degi[d], 1);
}

__global__ void k_scan1(const int* degi, int* rowptr, int* bsum) {
  __shared__ int s[256];
  int t = threadIdx.x;
  int i = blockIdx.x * 256 + t;
  int v = (i < NN) ? degi[i] : 0;
  s[t] = v;
  __syncthreads();
  for (int off = 1; off < 256; off <<= 1) {
    int x = (t >= off) ? s[t - off] : 0;
    __syncthreads();
    s[t] += x;
    __syncthreads();
  }
  if (i < NN) rowptr[i] = s[t] - v;
  if (t == 255) bsum[blockIdx.x] = s[255];
}

__global__ void k_scan2_gstats(int* bsum, int nb, const int* __restrict__ batch,
                               int* __restrict__ gstart, int* __restrict__ gcnti) {
  __shared__ int s[512];
  int t = threadIdx.x;
  int v = (t < nb) ? bsum[t] : 0;
  s[t] = v;
  __syncthreads();
  for (int off = 1; off < 512; off <<= 1) {
    int x = (t >= off) ? s[t - off] : 0;
    __syncthreads();
    s[t] += x;
    __syncthreads();
  }
  if (t < nb) bsum[t] = s[t] - v;
  if (t < NGR) {
    int g = t;
    int lo = 0, hi = NN;
    while (lo < hi) { int m = (lo + hi) >> 1; if (batch[m] < g) lo = m + 1; else hi = m; }
    int st = lo;
    hi = NN;
    while (lo < hi) { int m = (lo + hi) >> 1; if (batch[m] < g + 1) lo = m + 1; else hi = m; }
    gstart[g] = st;
    gcnti[g] = lo - st;
  }
}

__global__ void k_scan3_cursor(int* rowptr, const int* bsum, int* cursor,
                               const int* degi, float* inv_deg) {
  int i = blockIdx.x * 256 + threadIdx.x;
  if (i < NN) {
    int r = rowptr[i] + bsum[blockIdx.x];
    rowptr[i] = r;
    cursor[i] = r;
    inv_deg[i] = 1.f / fmaxf((float)degi[i], 1.f);
  }
  if (i == 0) rowptr[NN] = NE;
}

// ---------------- XCD-sliced scatter ----------------
__global__ void k_scatter8(const int* __restrict__ src, const int* __restrict__ dst,
                           int* cursor, int* csr) {
  int slice = blockIdx.x & (NSLICE - 1);
  int e = (blockIdx.x >> 3) * 256 + threadIdx.x;
  if (e >= NE) return;
  int d = dst[e];
  int lo = slice * SLICEW;
  if (d >= lo && d < lo + SLICEW) {
    int p = atomicAdd(&cursor[d], 1);
    csr[p] = src[e];
  }
}

// ---------------- dtype conversions ----------------
__global__ void k_cvt_x(const float* __restrict__ x, ushort_t* __restrict__ xb) {
  int i = blockIdx.x * 256 + threadIdx.x;
  if (i >= NN * FD / 8) return;
  const float4* p = (const float4*)x + (size_t)i * 2;
  float4 a = p[0], b = p[1];
  bf16x8 o;
  o[0] = (short)fbf(a.x); o[1] = (short)fbf(a.y);
  o[2] = (short)fbf(a.z); o[3] = (short)fbf(a.w);
  o[4] = (short)fbf(b.x); o[5] = (short)fbf(b.y);
  o[6] = (short)fbf(b.z); o[7] = (short)fbf(b.w);
  *(bf16x8*)&xb[(size_t)i * 8] = o;
}

__global__ void k_cvt_w(const float* __restrict__ W1, const float* __restrict__ W2,
                        ushort_t* __restrict__ W1t, ushort_t* __restrict__ W2t) {
  int idx = blockIdx.x * 256 + threadIdx.x;
  if (idx >= NLAYERS * FD * HD2) return;
  int l = idx >> 15, r = idx & 32767;
  {
    int n = r >> 7, k = r & 127;
    W1t[(size_t)l * 32768 + n * 128 + k] = fbf(W1[(size_t)l * 32768 + k * 256 + n]);
  }
  {
    int n = r >> 8, k = r & 255;
    W2t[(size_t)l * 32768 + n * 256 + k] = fbf(W2[(size_t)l * 32768 + k * 128 + n]);
  }
}

// ---------------- aggregation: 4 nodes per wave ----------------
__global__ void k_agg(const ushort_t* __restrict__ h, const int* __restrict__ rowptr,
                      const int* __restrict__ csr, const float* __restrict__ inv_deg,
                      ushort_t* __restrict__ tout, float* bnsum) {
  if (blockIdx.x == 0) {  // zero BN accumulators for this layer
    bnsum[threadIdx.x] = 0.f;
    bnsum[HD2 + threadIdx.x] = 0.f;
  }
  const int wave = threadIdx.x >> 6;
  const int lane = threadIdx.x & 63;
  const int q = lane >> 4, sub = lane & 15;
  const int node = blockIdx.x * 16 + wave * 4 + q;
  const uint4* h16 = (const uint4*)h;
  int beg = rowptr[node];
  int deg = rowptr[node + 1] - beg;
  int m1 = max(deg, __shfl_xor(deg, 16));
  int maxd = max(m1, __shfl_xor(m1, 32));
  float a0 = 0.f, a1 = 0.f, a2 = 0.f, a3 = 0.f;
  float a4 = 0.f, a5 = 0.f, a6 = 0.f, a7 = 0.f;
  int j = 0;
  for (; j + 8 <= maxd; j += 8) {
    uint4 p[8];
#pragma unroll
    for (int u = 0; u < 8; ++u) {
      bool valid = (j + u) < deg;
      int idx = beg + (valid ? j + u : 0);
      int s = csr[idx];
      uint4 v = h16[(size_t)s * 16 + sub];
      p[u].x = valid ? v.x : 0u;
      p[u].y = valid ? v.y : 0u;
      p[u].z = valid ? v.z : 0u;
      p[u].w = valid ? v.w : 0u;
    }
#pragma unroll
    for (int u = 0; u < 8; ++u) {
      a0 += bfl((unsigned short)(p[u].x & 0xFFFF));
      a1 += bfl((unsigned short)(p[u].x >> 16));
      a2 += bfl((unsigned short)(p[u].y & 0xFFFF));
      a3 += bfl((unsigned short)(p[u].y >> 16));
      a4 += bfl((unsigned short)(p[u].z & 0xFFFF));
      a5 += bfl((unsigned short)(p[u].z >> 16));
      a6 += bfl((unsigned short)(p[u].w & 0xFFFF));
      a7 += bfl((unsigned short)(p[u].w >> 16));
    }
  }
  for (; j < maxd; ++j) {
    bool valid = j < deg;
    int idx = beg + (valid ? j : 0);
    int s = csr[idx];
    uint4 v = h16[(size_t)s * 16 + sub];
    if (valid) {
      a0 += bfl((unsigned short)(v.x & 0xFFFF));
      a1 += bfl((unsigned short)(v.x >> 16));
      a2 += bfl((unsigned short)(v.y & 0xFFFF));
      a3 += bfl((unsigned short)(v.y >> 16));
      a4 += bfl((unsigned short)(v.z & 0xFFFF));
      a5 += bfl((unsigned short)(v.z >> 16));
      a6 += bfl((unsigned short)(v.w & 0xFFFF));
      a7 += bfl((unsigned short)(v.w >> 16));
    }
  }
  float id = inv_deg[node];
  uint4 c = h16[(size_t)node * 16 + sub];
  float o0 = bfl((unsigned short)(c.x & 0xFFFF)) + a0 * id;
  float o1 = bfl((unsigned short)(c.x >> 16)) + a1 * id;
  float o2 = bfl((unsigned short)(c.y & 0xFFFF)) + a2 * id;
  float o3 = bfl((unsigned short)(c.y >> 16)) + a3 * id;
  float o4 = bfl((unsigned short)(c.z & 0xFFFF)) + a4 * id;
  float o5 = bfl((unsigned short)(c.z >> 16)) + a5 * id;
  float o6 = bfl((unsigned short)(c.w & 0xFFFF)) + a6 * id;
  float o7 = bfl((unsigned short)(c.w >> 16)) + a7 * id;
  uint4 ow;
  ow.x = (unsigned)fbf(o0) | ((unsigned)fbf(o1) << 16);
  ow.y = (unsigned)fbf(o2) | ((unsigned)fbf(o3) << 16);
  ow.z = (unsigned)fbf(o4) | ((unsigned)fbf(o5) << 16);
  ow.w = (unsigned)fbf(o6) | ((unsigned)fbf(o7) << 16);
  ((uint4*)tout)[(size_t)node * 16 + sub] = ow;
}

// ---------------- ZSTAT: MFMA1 stats, A-fragments DIRECT from global (no As LDS, no main-loop barriers) ----------------
__launch_bounds__(256, 2)
__global__ void k_zstat(const ushort_t* __restrict__ A, const ushort_t* __restrict__ Bt,
                        const float* __restrict__ bias, float* __restrict__ bnsum) {
  __shared__ ushort_t Bs[256 * 128];  // 64KB swizzled
  __shared__ float ls[512];           // stat reduce
  const int tid = threadIdx.x;
#pragma unroll
  for (int i = 0; i < 16; ++i) {
    int chunk = tid + 256 * i;
    int n = chunk >> 4, c = chunk & 15;
    bf16x8 v = *(const bf16x8*)&Bt[n * 128 + c * 8];
    *(bf16x8*)((char*)Bs + n * 256 + ((c * 16) ^ ((n & 7) << 4))) = v;
  }
  __syncthreads();  // Bs ready (only barrier before the end reduce)
  const int wv = tid >> 6, ln = tid & 63;
  const int lr = ln & 15, lg = ln >> 4;
  float bb[16];
#pragma unroll
  for (int nt = 0; nt < 16; ++nt) bb[nt] = bias[nt * 16 + lr];
  float s0[16] = {}, s1[16] = {};

  for (int t = blockIdx.x; t < G1TILES; t += GEMM_GRID) {
    int row0 = t * 64;
    // A-fragments straight from global (same values/order as k_mlp => stats match bitwise)
    int ga = row0 + wv * 16 + lr; if (ga >= NN) ga = NN - 1;
    bf16x8 af[4];
#pragma unroll
    for (int ks = 0; ks < 4; ++ks)
      af[ks] = *(const bf16x8*)&A[(size_t)ga * FD + ks * 32 + lg * 8];
    f32x4 acc[16];
#pragma unroll
    for (int nt = 0; nt < 16; ++nt) acc[nt] = (f32x4){0.f, 0.f, 0.f, 0.f};
#pragma unroll
    for (int nt = 0; nt < 16; ++nt) {
      int bn = nt * 16 + lr;
#pragma unroll
      for (int ks = 0; ks < 4; ++ks) {
        bf16x8 bfr = *(bf16x8*)((char*)Bs + bn * 256 + ((ks * 64 + lg * 16) ^ ((bn & 7) << 4)));
        acc[nt] = __builtin_amdgcn_mfma_f32_16x16x32_bf16(af[ks], bfr, acc[nt], 0, 0, 0);
      }
    }
#pragma unroll
    for (int nt = 0; nt < 16; ++nt) {
#pragma unroll
      for (int j = 0; j < 4; ++j) {
        int grow = row0 + wv * 16 + lg * 4 + j;
        if (grow < NN) {
          float zf = acc[nt][j] + bb[nt];   // f32 Z, matches k_mlp bitwise
          s0[nt] += zf;
          s1[nt] += zf * zf;
        }
      }
    }
  }
  __syncthreads();
  ls[tid] = 0.f; ls[tid + 256] = 0.f;
  __syncthreads();
#pragma unroll
  for (int nt = 0; nt < 16; ++nt) {
    int col = nt * 16 + lr;
    atomicAdd(&ls[col], s0[nt]);
    atomicAdd(&ls[col + 256], s1[nt]);
  }
  __syncthreads();
  if (tid < 256) {
    atomicAdd(&bnsum[tid], ls[tid]);
    atomicAdd(&bnsum[HD2 + tid], ls[tid + 256]);
  }
}

// ---------------- fused MLP: H = relu(relu(BN(T@W1+b1)) @ W2 + b2), Z never global ----------------
__launch_bounds__(512, 2)
__global__ void k_mlp(const ushort_t* __restrict__ T, const ushort_t* __restrict__ W1t,
                      const ushort_t* __restrict__ W2t, const float* __restrict__ b1,
                      const float* __restrict__ b2, const float* __restrict__ bnsum,
                      const float* __restrict__ gamma, const float* __restrict__ beta,
                      ushort_t* __restrict__ Hout) {
  __shared__ ushort_t W1s[256 * 128];
  __shared__ ushort_t W2s[128 * 256];
  __shared__ ushort_t ZR[64 * 256];
  const int tid = threadIdx.x;
#pragma unroll
  for (int i = 0; i < 8; ++i) {
    int chunk = tid + 512 * i;
    int n = chunk >> 4, c = chunk & 15;
    bf16x8 v = *(const bf16x8*)&W1t[n * 128 + c * 8];
    *(bf16x8*)((char*)W1s + n * 256 + ((c * 16) ^ ((n & 7) << 4))) = v;
  }
#pragma unroll
  for (int i = 0; i < 8; ++i) {
    int chunk = tid + 512 * i;
    int n = chunk >> 5, c = chunk & 31;
    bf16x8 v = *(const bf16x8*)&W2t[n * 256 + c * 8];
    *(bf16x8*)((char*)W2s + n * 512 + ((c * 16) ^ ((n & 7) << 4))) = v;
  }
  const int wv = tid >> 6, ln = tid & 63;
  const int lr = ln & 15, lg = ln >> 4;
  const int mrow = (wv & 3) * 16;
  const int nh = wv >> 2;
  float a1v[8], a2v[8], bb1[8];
#pragma unroll
  for (int nt = 0; nt < 8; ++nt) {
    int c = (nh * 8 + nt) * 16 + lr;
    float mu = bnsum[c] * (1.f / (float)NN);
    float var = fmaxf(bnsum[HD2 + c] * (1.f / (float)NN) - mu * mu, 0.f);
    float g = gamma[c] * rsqrtf(var + BNEPS);
    a1v[nt] = g;
    a2v[nt] = beta[c] - mu * g;
    bb1[nt] = b1[c];
  }
  float bb2[4];
#pragma unroll
  for (int nt2 = 0; nt2 < 4; ++nt2) bb2[nt2] = b2[nh * 64 + nt2 * 16 + lr];
  __syncthreads();

  for (int t = blockIdx.x; t < G1TILES; t += MLP_GRID) {
    int row0 = t * 64;
    int grow = row0 + mrow + lr; if (grow >= NN) grow = NN - 1;
    bf16x8 af[4];
#pragma unroll
    for (int ks = 0; ks < 4; ++ks)
      af[ks] = *(const bf16x8*)&T[(size_t)grow * FD + ks * 32 + lg * 8];
    f32x4 acc1[8];
#pragma unroll
    for (int nt = 0; nt < 8; ++nt) acc1[nt] = (f32x4){0.f, 0.f, 0.f, 0.f};
#pragma unroll
    for (int nt = 0; nt < 8; ++nt) {
      int bn = (nh * 8 + nt) * 16 + lr;
#pragma unroll
      for (int ks = 0; ks < 4; ++ks) {
        bf16x8 bfr = *(bf16x8*)((char*)W1s + bn * 256 + ((ks * 64 + lg * 16) ^ ((bn & 7) << 4)));
        acc1[nt] = __builtin_amdgcn_mfma_f32_16x16x32_bf16(af[ks], bfr, acc1[nt], 0, 0, 0);
      }
    }
#pragma unroll
    for (int nt = 0; nt < 8; ++nt) {
      int col = (nh * 8 + nt) * 16 + lr;
#pragma unroll
      for (int j = 0; j < 4; ++j) {
        int row = mrow + lg * 4 + j;
        float z = acc1[nt][j] + bb1[nt];
        float f = fmaxf(z * a1v[nt] + a2v[nt], 0.f);
        int byte = row * 512 + ((((col >> 3) << 4) ^ ((row & 7) << 4))) + (col & 7) * 2;
        *(ushort_t*)((char*)ZR + byte) = fbf(f);
      }
    }
    __syncthreads();
    int zrow = mrow + lr;
    bf16x8 af2[8];
#pragma unroll
    for (int ks2 = 0; ks2 < 8; ++ks2) {
      int c2 = ks2 * 4 + lg;
      af2[ks2] = *(bf16x8*)((char*)ZR + zrow * 512 + ((c2 * 16) ^ ((zrow & 7) << 4)));
    }
    __syncthreads();
    f32x4 acc2[4];
#pragma unroll
    for (int nt2 = 0; nt2 < 4; ++nt2) acc2[nt2] = (f32x4){0.f, 0.f, 0.f, 0.f};
#pragma unroll
    for (int nt2 = 0; nt2 < 4; ++nt2) {
      int bn2 = nh * 64 + nt2 * 16 + lr;
#pragma unroll
      for (int ks2 = 0; ks2 < 8; ++ks2) {
        int c2 = ks2 * 4 + lg;
        bf16x8 bfr2 = *(bf16x8*)((char*)W2s + bn2 * 512 + ((c2 * 16) ^ ((bn2 & 7) << 4)));
        acc2[nt2] = __builtin_amdgcn_mfma_f32_16x16x32_bf16(af2[ks2], bfr2, acc2[nt2], 0, 0, 0);
      }
    }
#pragma unroll
    for (int nt2 = 0; nt2 < 4; ++nt2) {
      int col = nh * 64 + nt2 * 16 + lr;
#pragma unroll
      for (int j = 0; j < 4; ++j) {
        int hrow = row0 + mrow + lg * 4 + j;
        if (hrow < NN) Hout[(size_t)hrow * FD + col] = fbf(fmaxf(acc2[nt2][j] + bb2[nt2], 0.f));
      }
    }
  }
}

// ---------------- fused pool + FC + log_softmax ----------------
__launch_bounds__(256)
__global__ void k_pool_fc(const ushort_t* __restrict__ hb, const int* __restrict__ gstart,
                          const int* __restrict__ gcnti, const float* __restrict__ fcW,
                          const float* __restrict__ fcb, float* __restrict__ out) {
  __shared__ float pool4[4][512];
  __shared__ float wred[4][NCLS];
  int g = blockIdx.x, t = threadIdx.x;
  int start = gstart[g], cnt = gcnti[g];
  int chunk = t & 63, ro = t >> 6;
  int L = chunk >> 4, cc = (chunk & 15) * 8;
  const ushort_t* hL = hb + (size_t)L * NN * FD;
  float s[8] = {};
  for (int r = start + ro; r < start + cnt; r += 4) {
    bf16x8 v = *(const bf16x8*)&hL[(size_t)r * FD + cc];
#pragma unroll
    for (int j = 0; j < 8; ++j) s[j] += bfl((unsigned short)v[j]);
  }
#pragma unroll
  for (int j = 0; j < 8; ++j) pool4[ro][chunk * 8 + j] = s[j];
  __syncthreads();
  float inv = 1.f / fmaxf((float)cnt, 1.f);
  float pA = (pool4[0][t] + pool4[1][t] + pool4[2][t] + pool4[3][t]) * inv;
  float pB = (pool4[0][t + 256] + pool4[1][t + 256] + pool4[2][t + 256] + pool4[3][t + 256]) * inv;
  float pacc[NCLS];
#pragma unroll
  for (int c = 0; c < NCLS; ++c)
    pacc[c] = pA * fcW[t * NCLS + c] + pB * fcW[(t + 256) * NCLS + c];
#pragma unroll
  for (int off = 32; off > 0; off >>= 1)
#pragma unroll
    for (int c = 0; c < NCLS; ++c) pacc[c] += __shfl_down(pacc[c], off);
  if ((t & 63) == 0)
#pragma unroll
    for (int c = 0; c < NCLS; ++c) wred[t >> 6][c] = pacc[c];
  __syncthreads();
  if (t == 0) {
    float lg[NCLS];
    float mx = -1e30f;
#pragma unroll
    for (int c = 0; c < NCLS; ++c) {
      lg[c] = wred[0][c] + wred[1][c] + wred[2][c] + wred[3][c] + fcb[c];
      mx = fmaxf(mx, lg[c]);
    }
    float se = 0.f;
#pragma unroll
    for (int c = 0; c < NCLS; ++c) se += expf(lg[c] - mx);
    float lse = mx + logf(se);
#pragma unroll
    for (int c = 0; c < NCLS; ++c) out[(size_t)g * NCLS + c] = lg[c] - lse;
  }
}

// ---------------- host ----------------
extern "C" void kernel_launch(void* const* d_in, const int* in_sizes, int n_in,
                              void* d_out, int out_size, void* d_ws, size_t ws_size,
                              hipStream_t stream) {
  const float* x      = (const float*)d_in[0];
  const int*   ei     = (const int*)d_in[1];
  const int*   batch  = (const int*)d_in[3];
  const float* W1     = (const float*)d_in[4];
  const float* b1     = (const float*)d_in[5];
  const float* gamma1 = (const float*)d_in[6];
  const float* beta1  = (const float*)d_in[7];
  const float* W2     = (const float*)d_in[8];
  const float* b2     = (const float*)d_in[9];
  const float* fcW    = (const float*)d_in[10];
  const float* fcb    = (const float*)d_in[11];
  float* out = (float*)d_out;

  char* p = (char*)d_ws;
  auto alloc = [&](size_t bytes) {
    char* r = p;
    p += (bytes + 255) & ~(size_t)255;
    return r;
  };
  ushort_t* xbf   = (ushort_t*)alloc((size_t)NN * FD * 2);
  ushort_t* tbuf  = (ushort_t*)alloc((size_t)NN * FD * 2);
  ushort_t* hb    = (ushort_t*)alloc((size_t)NLAYERS * NN * FD * 2);
  ushort_t* W1t   = (ushort_t*)alloc((size_t)NLAYERS * FD * HD2 * 2);
  ushort_t* W2t   = (ushort_t*)alloc((size_t)NLAYERS * FD * HD2 * 2);
  float* inv_deg  = (float*)alloc((size_t)NN * 4);
  float* bnsum    = (float*)alloc(2 * HD2 * 4);
  int* degi       = (int*)alloc((size_t)NN * 4);
  int* rowptr     = (int*)alloc((size_t)(NN + 1) * 4);
  int* cursor     = (int*)alloc((size_t)NN * 4);
  int* csr        = (int*)alloc((size_t)NE * 4);
  int* bsum       = (int*)alloc(512 * 4);
  int* src32      = (int*)alloc((size_t)NE * 4);
  int* dst32      = (int*)alloc((size_t)NE * 4);
  int* batch32    = (int*)alloc((size_t)NN * 4);
  int* gcnti      = (int*)alloc((size_t)NGR * 4);
  int* gstart     = (int*)alloc((size_t)NGR * 4);
  int* flag       = (int*)alloc(256);

  k_init_detect<<<NB, 256, 0, stream>>>(ei, flag, degi);
  k_repack<<<EB, 256, 0, stream>>>(ei, batch, flag, src32, dst32, batch32);
  k_deg8<<<EB * NSLICE, 256, 0, stream>>>(dst32, degi);
  k_scan1<<<NB, 256, 0, stream>>>(degi, rowptr, bsum);
  k_scan2_gstats<<<1, 512, 0, stream>>>(bsum, NB, batch32, gstart, gcnti);
  k_scan3_cursor<<<NB, 256, 0, stream>>>(rowptr, bsum, cursor, degi, inv_deg);
  k_scatter8<<<EB * NSLICE, 256, 0, stream>>>(src32, dst32, cursor, csr);
  k_cvt_x<<<(NN * FD / 8 + 255) / 256, 256, 0, stream>>>(x, xbf);
  k_cvt_w<<<(NLAYERS * FD * HD2 + 255) / 256, 256, 0, stream>>>(W1, W2, W1t, W2t);

  const ushort_t* hin = xbf;
  for (int L = 0; L < NLAYERS; ++L) {
    k_agg<<<NN / 16, 256, 0, stream>>>(hin, rowptr, csr, inv_deg, tbuf, bnsum);
    k_zstat<<<GEMM_GRID, 256, 0, stream>>>(tbuf, W1t + (size_t)L * FD * HD2,
                                           b1 + (size_t)L * HD2, bnsum);
    k_mlp<<<MLP_GRID, 512, 0, stream>>>(tbuf, W1t + (size_t)L * FD * HD2,
                                        W2t + (size_t)L * FD * HD2,
                                        b1 + (size_t)L * HD2, b2 + (size_t)L * FD,
                                        bnsum, gamma1 + (size_t)L * HD2,
                                        beta1 + (size_t)L * HD2,
                                        hb + (size_t)L * NN * FD);
    hin = hb + (size_t)L * NN * FD;
  }
  k_pool_fc<<<NGR, 256, 0, stream>>>(hb, gstart, gcnti, fcW, fcb, out);
}

// Round 21
// 720.517 us; speedup vs baseline: 1.2586x; 1.2586x over previous
//
#include <hip/hip_runtime.h>
#include <cstdint>
#include <cstddef>

#define NN 100000      // nodes
#define NE 1600000     // edges
#define FD 128         // feature dim
#define HD2 256        // hidden*2
#define NLAYERS 4
#define NGR 512        // graphs
#define NCLS 10
#define BNEPS 1e-5f
#define G1TILES 1563   // ceil(NN/64)
#define GEMM_GRID 512  // zstat grid: 2 blocks/CU co-resident exactly
#define MLP_GRID 256   // k_mlp grid (1 block/CU)
#define EB 6250        // edge blocks (NE/256)
#define NB 391         // node blocks ceil(NN/256)
#define NSLICE 8       // XCD slices for scatter/deg
#define SLICEW 12500   // node range per slice (NN/8)

typedef unsigned short ushort_t;
typedef short bf16x8 __attribute__((ext_vector_type(8)));
typedef float f32x4 __attribute__((ext_vector_type(4)));

__device__ __forceinline__ float bfl(unsigned short u) {
  unsigned v = ((unsigned)u) << 16;
  return __builtin_bit_cast(float, v);
}
__device__ __forceinline__ unsigned short fbf(float f) {
  unsigned u = __builtin_bit_cast(unsigned, f);
  unsigned r = (u + 0x7FFFu + ((u >> 16) & 1u)) >> 16;
  return (unsigned short)r;
}

// ---------------- fused init (degi=0) + int64 detect ----------------
__global__ void k_init_detect(const int* ei, int* flag, int* degi) {
  int i = blockIdx.x * 256 + threadIdx.x;
  if (i < NN) degi[i] = 0;
  if (blockIdx.x == 0) {
    __shared__ int nz;
    if (threadIdx.x == 0) nz = 0;
    __syncthreads();
    if (ei[2 * threadIdx.x + 1] != 0) atomicAdd(&nz, 1);
    __syncthreads();
    if (threadIdx.x == 0) flag[0] = (nz == 0) ? 1 : 0;  // 1 => int64
  }
}

// ---------------- pure repack ----------------
__global__ void k_repack(const int* ei, const int* batch, const int* flag,
                         int* src32, int* dst32, int* batch32) {
  int i = blockIdx.x * 256 + threadIdx.x;
  const bool wide = (flag[0] != 0);
  if (i < NE) {
    src32[i] = wide ? ei[2 * i] : ei[i];
    dst32[i] = wide ? ei[2 * (NE + i)] : ei[NE + i];
  }
  if (i < NN) batch32[i] = wide ? batch[2 * i] : batch[i];
}

// ---------------- XCD-sliced degree histogram ----------------
__global__ void k_deg8(const int* __restrict__ dst, int* degi) {
  int slice = blockIdx.x & (NSLICE - 1);
  int e = (blockIdx.x >> 3) * 256 + threadIdx.x;
  if (e >= NE) return;
  int d = dst[e];
  int lo = slice * SLICEW;
  if (d >= lo && d < lo + SLICEW) atomicAdd(&degi[d], 1);
}

__global__ void k_scan1(const int* degi, int* rowptr, int* bsum) {
  __shared__ int s[256];
  int t = threadIdx.x;
  int i = blockIdx.x * 256 + t;
  int v = (i < NN) ? degi[i] : 0;
  s[t] = v;
  __syncthreads();
  for (int off = 1; off < 256; off <<= 1) {
    int x = (t >= off) ? s[t - off] : 0;
    __syncthreads();
    s[t] += x;
    __syncthreads();
  }
  if (i < NN) rowptr[i] = s[t] - v;
  if (t == 255) bsum[blockIdx.x] = s[255];
}

__global__ void k_scan2_gstats(int* bsum, int nb, const int* __restrict__ batch,
                               int* __restrict__ gstart, int* __restrict__ gcnti) {
  __shared__ int s[512];
  int t = threadIdx.x;
  int v = (t < nb) ? bsum[t] : 0;
  s[t] = v;
  __syncthreads();
  for (int off = 1; off < 512; off <<= 1) {
    int x = (t >= off) ? s[t - off] : 0;
    __syncthreads();
    s[t] += x;
    __syncthreads();
  }
  if (t < nb) bsum[t] = s[t] - v;
  if (t < NGR) {
    int g = t;
    int lo = 0, hi = NN;
    while (lo < hi) { int m = (lo + hi) >> 1; if (batch[m] < g) lo = m + 1; else hi = m; }
    int st = lo;
    hi = NN;
    while (lo < hi) { int m = (lo + hi) >> 1; if (batch[m] < g + 1) lo = m + 1; else hi = m; }
    gstart[g] = st;
    gcnti[g] = lo - st;
  }
}

__global__ void k_scan3_cursor(int* rowptr, const int* bsum, int* cursor,
                               const int* degi, float* inv_deg) {
  int i = blockIdx.x * 256 + threadIdx.x;
  if (i < NN) {
    int r = rowptr[i] + bsum[blockIdx.x];
    rowptr[i] = r;
    cursor[i] = r;
    inv_deg[i] = 1.f / fmaxf((float)degi[i], 1.f);
  }
  if (i == 0) rowptr[NN] = NE;
}

// ---------------- XCD-sliced scatter ----------------
__global__ void k_scatter8(const int* __restrict__ src, const int* __restrict__ dst,
                           int* cursor, int* csr) {
  int slice = blockIdx.x & (NSLICE - 1);
  int e = (blockIdx.x >> 3) * 256 + threadIdx.x;
  if (e >= NE) return;
  int d = dst[e];
  int lo = slice * SLICEW;
  if (d >= lo && d < lo + SLICEW) {
    int p = atomicAdd(&cursor[d], 1);
    csr[p] = src[e];
  }
}

// ---------------- dtype conversions ----------------
__global__ void k_cvt_x(const float* __restrict__ x, ushort_t* __restrict__ xb) {
  int i = blockIdx.x * 256 + threadIdx.x;
  if (i >= NN * FD / 8) return;
  const float4* p = (const float4*)x + (size_t)i * 2;
  float4 a = p[0], b = p[1];
  bf16x8 o;
  o[0] = (short)fbf(a.x); o[1] = (short)fbf(a.y);
  o[2] = (short)fbf(a.z); o[3] = (short)fbf(a.w);
  o[4] = (short)fbf(b.x); o[5] = (short)fbf(b.y);
  o[6] = (short)fbf(b.z); o[7] = (short)fbf(b.w);
  *(bf16x8*)&xb[(size_t)i * 8] = o;
}

__global__ void k_cvt_w(const float* __restrict__ W1, const float* __restrict__ W2,
                        ushort_t* __restrict__ W1t, ushort_t* __restrict__ W2t) {
  int idx = blockIdx.x * 256 + threadIdx.x;
  if (idx >= NLAYERS * FD * HD2) return;
  int l = idx >> 15, r = idx & 32767;
  {
    int n = r >> 7, k = r & 127;
    W1t[(size_t)l * 32768 + n * 128 + k] = fbf(W1[(size_t)l * 32768 + k * 256 + n]);
  }
  {
    int n = r >> 8, k = r & 255;
    W2t[(size_t)l * 32768 + n * 256 + k] = fbf(W2[(size_t)l * 32768 + k * 128 + n]);
  }
}

// ---------------- aggregation: 4 nodes per wave ----------------
__global__ void k_agg(const ushort_t* __restrict__ h, const int* __restrict__ rowptr,
                      const int* __restrict__ csr, const float* __restrict__ inv_deg,
                      ushort_t* __restrict__ tout, float* bnsum) {
  if (blockIdx.x == 0) {  // zero BN accumulators for this layer
    bnsum[threadIdx.x] = 0.f;
    bnsum[HD2 + threadIdx.x] = 0.f;
  }
  const int wave = threadIdx.x >> 6;
  const int lane = threadIdx.x & 63;
  const int q = lane >> 4, sub = lane & 15;
  const int node = blockIdx.x * 16 + wave * 4 + q;
  const uint4* h16 = (const uint4*)h;
  int beg = rowptr[node];
  int deg = rowptr[node + 1] - beg;
  int m1 = max(deg, __shfl_xor(deg, 16));
  int maxd = max(m1, __shfl_xor(m1, 32));
  float a0 = 0.f, a1 = 0.f, a2 = 0.f, a3 = 0.f;
  float a4 = 0.f, a5 = 0.f, a6 = 0.f, a7 = 0.f;
  int j = 0;
  for (; j + 8 <= maxd; j += 8) {
    uint4 p[8];
#pragma unroll
    for (int u = 0; u < 8; ++u) {
      bool valid = (j + u) < deg;
      int idx = beg + (valid ? j + u : 0);
      int s = csr[idx];
      uint4 v = h16[(size_t)s * 16 + sub];
      p[u].x = valid ? v.x : 0u;
      p[u].y = valid ? v.y : 0u;
      p[u].z = valid ? v.z : 0u;
      p[u].w = valid ? v.w : 0u;
    }
#pragma unroll
    for (int u = 0; u < 8; ++u) {
      a0 += bfl((unsigned short)(p[u].x & 0xFFFF));
      a1 += bfl((unsigned short)(p[u].x >> 16));
      a2 += bfl((unsigned short)(p[u].y & 0xFFFF));
      a3 += bfl((unsigned short)(p[u].y >> 16));
      a4 += bfl((unsigned short)(p[u].z & 0xFFFF));
      a5 += bfl((unsigned short)(p[u].z >> 16));
      a6 += bfl((unsigned short)(p[u].w & 0xFFFF));
      a7 += bfl((unsigned short)(p[u].w >> 16));
    }
  }
  for (; j < maxd; ++j) {
    bool valid = j < deg;
    int idx = beg + (valid ? j : 0);
    int s = csr[idx];
    uint4 v = h16[(size_t)s * 16 + sub];
    if (valid) {
      a0 += bfl((unsigned short)(v.x & 0xFFFF));
      a1 += bfl((unsigned short)(v.x >> 16));
      a2 += bfl((unsigned short)(v.y & 0xFFFF));
      a3 += bfl((unsigned short)(v.y >> 16));
      a4 += bfl((unsigned short)(v.z & 0xFFFF));
      a5 += bfl((unsigned short)(v.z >> 16));
      a6 += bfl((unsigned short)(v.w & 0xFFFF));
      a7 += bfl((unsigned short)(v.w >> 16));
    }
  }
  float id = inv_deg[node];
  uint4 c = h16[(size_t)node * 16 + sub];
  float o0 = bfl((unsigned short)(c.x & 0xFFFF)) + a0 * id;
  float o1 = bfl((unsigned short)(c.x >> 16)) + a1 * id;
  float o2 = bfl((unsigned short)(c.y & 0xFFFF)) + a2 * id;
  float o3 = bfl((unsigned short)(c.y >> 16)) + a3 * id;
  float o4 = bfl((unsigned short)(c.z & 0xFFFF)) + a4 * id;
  float o5 = bfl((unsigned short)(c.z >> 16)) + a5 * id;
  float o6 = bfl((unsigned short)(c.w & 0xFFFF)) + a6 * id;
  float o7 = bfl((unsigned short)(c.w >> 16)) + a7 * id;
  uint4 ow;
  ow.x = (unsigned)fbf(o0) | ((unsigned)fbf(o1) << 16);
  ow.y = (unsigned)fbf(o2) | ((unsigned)fbf(o3) << 16);
  ow.z = (unsigned)fbf(o4) | ((unsigned)fbf(o5) << 16);
  ow.w = (unsigned)fbf(o6) | ((unsigned)fbf(o7) << 16);
  ((uint4*)tout)[(size_t)node * 16 + sub] = ow;
}

// ---------------- ZSTAT: MFMA1 stats only (no Z store); A staged via LDS (coalesced) ----------------
__launch_bounds__(256, 2)
__global__ void k_zstat(const ushort_t* __restrict__ A, const ushort_t* __restrict__ Bt,
                        const float* __restrict__ bias, float* __restrict__ bnsum) {
  __shared__ ushort_t Bs[256 * 128];  // 64KB swizzled
  __shared__ ushort_t As[64 * 128];   // 16KB swizzled (reused for stat reduce)
  const int tid = threadIdx.x;
#pragma unroll
  for (int i = 0; i < 16; ++i) {
    int chunk = tid + 256 * i;
    int n = chunk >> 4, c = chunk & 15;
    bf16x8 v = *(const bf16x8*)&Bt[n * 128 + c * 8];
    *(bf16x8*)((char*)Bs + n * 256 + ((c * 16) ^ ((n & 7) << 4))) = v;
  }
  const int wv = tid >> 6, ln = tid & 63;
  const int lr = ln & 15, lg = ln >> 4;
  float bb[16];
#pragma unroll
  for (int nt = 0; nt < 16; ++nt) bb[nt] = bias[nt * 16 + lr];
  float s0[16] = {}, s1[16] = {};

  for (int t = blockIdx.x; t < G1TILES; t += GEMM_GRID) {
    int row0 = t * 64;
#pragma unroll
    for (int i = 0; i < 4; ++i) {
      int chunk = tid + 256 * i;
      int r = chunk >> 4, c = chunk & 15;
      int grow = row0 + r; if (grow >= NN) grow = NN - 1;
      bf16x8 v = *(const bf16x8*)&A[(size_t)grow * FD + c * 8];
      *(bf16x8*)((char*)As + r * 256 + ((c * 16) ^ ((r & 7) << 4))) = v;
    }
    __syncthreads();
    int arow = wv * 16 + lr;
    bf16x8 af[4];
#pragma unroll
    for (int ks = 0; ks < 4; ++ks)
      af[ks] = *(bf16x8*)((char*)As + arow * 256 + ((ks * 64 + lg * 16) ^ ((arow & 7) << 4)));
    f32x4 acc[16];
#pragma unroll
    for (int nt = 0; nt < 16; ++nt) acc[nt] = (f32x4){0.f, 0.f, 0.f, 0.f};
#pragma unroll
    for (int nt = 0; nt < 16; ++nt) {
      int bn = nt * 16 + lr;
#pragma unroll
      for (int ks = 0; ks < 4; ++ks) {
        bf16x8 bfr = *(bf16x8*)((char*)Bs + bn * 256 + ((ks * 64 + lg * 16) ^ ((bn & 7) << 4)));
        acc[nt] = __builtin_amdgcn_mfma_f32_16x16x32_bf16(af[ks], bfr, acc[nt], 0, 0, 0);
      }
    }
    __syncthreads();
#pragma unroll
    for (int nt = 0; nt < 16; ++nt) {
#pragma unroll
      for (int j = 0; j < 4; ++j) {
        int grow = row0 + wv * 16 + lg * 4 + j;
        if (grow < NN) {
          float zf = acc[nt][j] + bb[nt];   // f32 Z, matches k_mlp's recompute bitwise
          s0[nt] += zf;
          s1[nt] += zf * zf;
        }
      }
    }
  }
  __syncthreads();
  float* ls = (float*)As;
  ls[tid] = 0.f; ls[tid + 256] = 0.f;
  __syncthreads();
#pragma unroll
  for (int nt = 0; nt < 16; ++nt) {
    int col = nt * 16 + lr;
    atomicAdd(&ls[col], s0[nt]);
    atomicAdd(&ls[col + 256], s1[nt]);
  }
  __syncthreads();
  if (tid < 256) {
    atomicAdd(&bnsum[tid], ls[tid]);
    atomicAdd(&bnsum[HD2 + tid], ls[tid + 256]);
  }
}

// ---------------- fused MLP: H = relu(relu(BN(T@W1+b1)) @ W2 + b2), Z never global ----------------
__launch_bounds__(512, 2)
__global__ void k_mlp(const ushort_t* __restrict__ T, const ushort_t* __restrict__ W1t,
                      const ushort_t* __restrict__ W2t, const float* __restrict__ b1,
                      const float* __restrict__ b2, const float* __restrict__ bnsum,
                      const float* __restrict__ gamma, const float* __restrict__ beta,
                      ushort_t* __restrict__ Hout) {
  __shared__ ushort_t W1s[256 * 128];
  __shared__ ushort_t W2s[128 * 256];
  __shared__ ushort_t ZR[64 * 256];
  const int tid = threadIdx.x;
#pragma unroll
  for (int i = 0; i < 8; ++i) {
    int chunk = tid + 512 * i;
    int n = chunk >> 4, c = chunk & 15;
    bf16x8 v = *(const bf16x8*)&W1t[n * 128 + c * 8];
    *(bf16x8*)((char*)W1s + n * 256 + ((c * 16) ^ ((n & 7) << 4))) = v;
  }
#pragma unroll
  for (int i = 0; i < 8; ++i) {
    int chunk = tid + 512 * i;
    int n = chunk >> 5, c = chunk & 31;
    bf16x8 v = *(const bf16x8*)&W2t[n * 256 + c * 8];
    *(bf16x8*)((char*)W2s + n * 512 + ((c * 16) ^ ((n & 7) << 4))) = v;
  }
  const int wv = tid >> 6, ln = tid & 63;
  const int lr = ln & 15, lg = ln >> 4;
  const int mrow = (wv & 3) * 16;
  const int nh = wv >> 2;
  float a1v[8], a2v[8], bb1[8];
#pragma unroll
  for (int nt = 0; nt < 8; ++nt) {
    int c = (nh * 8 + nt) * 16 + lr;
    float mu = bnsum[c] * (1.f / (float)NN);
    float var = fmaxf(bnsum[HD2 + c] * (1.f / (float)NN) - mu * mu, 0.f);
    float g = gamma[c] * rsqrtf(var + BNEPS);
    a1v[nt] = g;
    a2v[nt] = beta[c] - mu * g;
    bb1[nt] = b1[c];
  }
  float bb2[4];
#pragma unroll
  for (int nt2 = 0; nt2 < 4; ++nt2) bb2[nt2] = b2[nh * 64 + nt2 * 16 + lr];
  __syncthreads();

  for (int t = blockIdx.x; t < G1TILES; t += MLP_GRID) {
    int row0 = t * 64;
    int grow = row0 + mrow + lr; if (grow >= NN) grow = NN - 1;
    bf16x8 af[4];
#pragma unroll
    for (int ks = 0; ks < 4; ++ks)
      af[ks] = *(const bf16x8*)&T[(size_t)grow * FD + ks * 32 + lg * 8];
    f32x4 acc1[8];
#pragma unroll
    for (int nt = 0; nt < 8; ++nt) acc1[nt] = (f32x4){0.f, 0.f, 0.f, 0.f};
#pragma unroll
    for (int nt = 0; nt < 8; ++nt) {
      int bn = (nh * 8 + nt) * 16 + lr;
#pragma unroll
      for (int ks = 0; ks < 4; ++ks) {
        bf16x8 bfr = *(bf16x8*)((char*)W1s + bn * 256 + ((ks * 64 + lg * 16) ^ ((bn & 7) << 4)));
        acc1[nt] = __builtin_amdgcn_mfma_f32_16x16x32_bf16(af[ks], bfr, acc1[nt], 0, 0, 0);
      }
    }
#pragma unroll
    for (int nt = 0; nt < 8; ++nt) {
      int col = (nh * 8 + nt) * 16 + lr;
#pragma unroll
      for (int j = 0; j < 4; ++j) {
        int row = mrow + lg * 4 + j;
        float z = acc1[nt][j] + bb1[nt];
        float f = fmaxf(z * a1v[nt] + a2v[nt], 0.f);
        int byte = row * 512 + ((((col >> 3) << 4) ^ ((row & 7) << 4))) + (col & 7) * 2;
        *(ushort_t*)((char*)ZR + byte) = fbf(f);
      }
    }
    __syncthreads();
    int zrow = mrow + lr;
    bf16x8 af2[8];
#pragma unroll
    for (int ks2 = 0; ks2 < 8; ++ks2) {
      int c2 = ks2 * 4 + lg;
      af2[ks2] = *(bf16x8*)((char*)ZR + zrow * 512 + ((c2 * 16) ^ ((zrow & 7) << 4)));
    }
    __syncthreads();
    f32x4 acc2[4];
#pragma unroll
    for (int nt2 = 0; nt2 < 4; ++nt2) acc2[nt2] = (f32x4){0.f, 0.f, 0.f, 0.f};
#pragma unroll
    for (int nt2 = 0; nt2 < 4; ++nt2) {
      int bn2 = nh * 64 + nt2 * 16 + lr;
#pragma unroll
      for (int ks2 = 0; ks2 < 8; ++ks2) {
        int c2 = ks2 * 4 + lg;
        bf16x8 bfr2 = *(bf16x8*)((char*)W2s + bn2 * 512 + ((c2 * 16) ^ ((bn2 & 7) << 4)));
        acc2[nt2] = __builtin_amdgcn_mfma_f32_16x16x32_bf16(af2[ks2], bfr2, acc2[nt2], 0, 0, 0);
      }
    }
#pragma unroll
    for (int nt2 = 0; nt2 < 4; ++nt2) {
      int col = nh * 64 + nt2 * 16 + lr;
#pragma unroll
      for (int j = 0; j < 4; ++j) {
        int hrow = row0 + mrow + lg * 4 + j;
        if (hrow < NN) Hout[(size_t)hrow * FD + col] = fbf(fmaxf(acc2[nt2][j] + bb2[nt2], 0.f));
      }
    }
  }
}

// ---------------- fused pool + FC + log_softmax ----------------
__launch_bounds__(256)
__global__ void k_pool_fc(const ushort_t* __restrict__ hb, const int* __restrict__ gstart,
                          const int* __restrict__ gcnti, const float* __restrict__ fcW,
                          const float* __restrict__ fcb, float* __restrict__ out) {
  __shared__ float pool4[4][512];
  __shared__ float wred[4][NCLS];
  int g = blockIdx.x, t = threadIdx.x;
  int start = gstart[g], cnt = gcnti[g];
  int chunk = t & 63, ro = t >> 6;
  int L = chunk >> 4, cc = (chunk & 15) * 8;
  const ushort_t* hL = hb + (size_t)L * NN * FD;
  float s[8] = {};
  for (int r = start + ro; r < start + cnt; r += 4) {
    bf16x8 v = *(const bf16x8*)&hL[(size_t)r * FD + cc];
#pragma unroll
    for (int j = 0; j < 8; ++j) s[j] += bfl((unsigned short)v[j]);
  }
#pragma unroll
  for (int j = 0; j < 8; ++j) pool4[ro][chunk * 8 + j] = s[j];
  __syncthreads();
  float inv = 1.f / fmaxf((float)cnt, 1.f);
  float pA = (pool4[0][t] + pool4[1][t] + pool4[2][t] + pool4[3][t]) * inv;
  float pB = (pool4[0][t + 256] + pool4[1][t + 256] + pool4[2][t + 256] + pool4[3][t + 256]) * inv;
  float pacc[NCLS];
#pragma unroll
  for (int c = 0; c < NCLS; ++c)
    pacc[c] = pA * fcW[t * NCLS + c] + pB * fcW[(t + 256) * NCLS + c];
#pragma unroll
  for (int off = 32; off > 0; off >>= 1)
#pragma unroll
    for (int c = 0; c < NCLS; ++c) pacc[c] += __shfl_down(pacc[c], off);
  if ((t & 63) == 0)
#pragma unroll
    for (int c = 0; c < NCLS; ++c) wred[t >> 6][c] = pacc[c];
  __syncthreads();
  if (t == 0) {
    float lg[NCLS];
    float mx = -1e30f;
#pragma unroll
    for (int c = 0; c < NCLS; ++c) {
      lg[c] = wred[0][c] + wred[1][c] + wred[2][c] + wred[3][c] + fcb[c];
      mx = fmaxf(mx, lg[c]);
    }
    float se = 0.f;
#pragma unroll
    for (int c = 0; c < NCLS; ++c) se += expf(lg[c] - mx);
    float lse = mx + logf(se);
#pragma unroll
    for (int c = 0; c < NCLS; ++c) out[(size_t)g * NCLS + c] = lg[c] - lse;
  }
}

// ---------------- host ----------------
extern "C" void kernel_launch(void* const* d_in, const int* in_sizes, int n_in,
                              void* d_out, int out_size, void* d_ws, size_t ws_size,
                              hipStream_t stream) {
  const float* x      = (const float*)d_in[0];
  const int*   ei     = (const int*)d_in[1];
  const int*   batch  = (const int*)d_in[3];
  const float* W1     = (const float*)d_in[4];
  const float* b1     = (const float*)d_in[5];
  const float* gamma1 = (const float*)d_in[6];
  const float* beta1  = (const float*)d_in[7];
  const float* W2     = (const float*)d_in[8];
  const float* b2     = (const float*)d_in[9];
  const float* fcW    = (const float*)d_in[10];
  const float* fcb    = (const float*)d_in[11];
  float* out = (float*)d_out;

  char* p = (char*)d_ws;
  auto alloc = [&](size_t bytes) {
    char* r = p;
    p += (bytes + 255) & ~(size_t)255;
    return r;
  };
  ushort_t* xbf   = (ushort_t*)alloc((size_t)NN * FD * 2);
  ushort_t* tbuf  = (ushort_t*)alloc((size_t)NN * FD * 2);
  ushort_t* hb    = (ushort_t*)alloc((size_t)NLAYERS * NN * FD * 2);
  ushort_t* W1t   = (ushort_t*)alloc((size_t)NLAYERS * FD * HD2 * 2);
  ushort_t* W2t   = (ushort_t*)alloc((size_t)NLAYERS * FD * HD2 * 2);
  float* inv_deg  = (float*)alloc((size_t)NN * 4);
  float* bnsum    = (float*)alloc(2 * HD2 * 4);
  int* degi       = (int*)alloc((size_t)NN * 4);
  int* rowptr     = (int*)alloc((size_t)(NN + 1) * 4);
  int* cursor     = (int*)alloc((size_t)NN * 4);
  int* csr        = (int*)alloc((size_t)NE * 4);
  int* bsum       = (int*)alloc(512 * 4);
  int* src32      = (int*)alloc((size_t)NE * 4);
  int* dst32      = (int*)alloc((size_t)NE * 4);
  int* batch32    = (int*)alloc((size_t)NN * 4);
  int* gcnti      = (int*)alloc((size_t)NGR * 4);
  int* gstart     = (int*)alloc((size_t)NGR * 4);
  int* flag       = (int*)alloc(256);

  k_init_detect<<<NB, 256, 0, stream>>>(ei, flag, degi);
  k_repack<<<EB, 256, 0, stream>>>(ei, batch, flag, src32, dst32, batch32);
  k_deg8<<<EB * NSLICE, 256, 0, stream>>>(dst32, degi);
  k_scan1<<<NB, 256, 0, stream>>>(degi, rowptr, bsum);
  k_scan2_gstats<<<1, 512, 0, stream>>>(bsum, NB, batch32, gstart, gcnti);
  k_scan3_cursor<<<NB, 256, 0, stream>>>(rowptr, bsum, cursor, degi, inv_deg);
  k_scatter8<<<EB * NSLICE, 256, 0, stream>>>(src32, dst32, cursor, csr);
  k_cvt_x<<<(NN * FD / 8 + 255) / 256, 256, 0, stream>>>(x, xbf);
  k_cvt_w<<<(NLAYERS * FD * HD2 + 255) / 256, 256, 0, stream>>>(W1, W2, W1t, W2t);

  const ushort_t* hin = xbf;
  for (int L = 0; L < NLAYERS; ++L) {
    k_agg<<<NN / 16, 256, 0, stream>>>(hin, rowptr, csr, inv_deg, tbuf, bnsum);
    k_zstat<<<GEMM_GRID, 256, 0, stream>>>(tbuf, W1t + (size_t)L * FD * HD2,
                                           b1 + (size_t)L * HD2, bnsum);
    k_mlp<<<MLP_GRID, 512, 0, stream>>>(tbuf, W1t + (size_t)L * FD * HD2,
                                        W2t + (size_t)L * FD * HD2,
                                        b1 + (size_t)L * HD2, b2 + (size_t)L * FD,
                                        bnsum, gamma1 + (size_t)L * HD2,
                                        beta1 + (size_t)L * HD2,
                                        hb + (size_t)L * NN * FD);
    hin = hb + (size_t)L * NN * FD;
  }
  k_pool_fc<<<NGR, 256, 0, stream>>>(hb, gstart, gcnti, fcW, fcb, out);
}